// Round 2
// baseline (118.232 us; speedup 1.0000x reference)
//
#include <hip/hip_runtime.h>
#include <hip/hip_bf16.h>

typedef float  f32x16 __attribute__((ext_vector_type(16)));
typedef short  bf16x8 __attribute__((ext_vector_type(8)));

__device__ __forceinline__ unsigned short f2bf(float x) {
  union { float f; unsigned u; } v; v.f = x;
  return (unsigned short)((v.u + 0x7FFFu + ((v.u >> 16) & 1u)) >> 16);
}

__device__ __forceinline__ float celu1(float x) {
  return x > 0.f ? x : (__expf(x) - 1.f);
}

struct Stage { float4 a[4][2]; };  // one node's 32x64 f32 neighbor tile slice per lane

__device__ __forceinline__ void issue_stage(Stage& s, const float* __restrict__ aptr,
                                            int lo, int hi) {
#pragma unroll
  for (int ks = 0; ks < 4; ++ks) {
    const float* pa = aptr + lo * 64 + ks * 16 + 8 * hi;
    s.a[ks][0] = *reinterpret_cast<const float4*>(pa);
    s.a[ks][1] = *reinterpret_cast<const float4*>(pa + 4);
  }
}

__device__ __forceinline__ bf16x8 to_frag(float4 a, float4 b) {
  bf16x8 r;
  r[0] = (short)f2bf(a.x); r[1] = (short)f2bf(a.y);
  r[2] = (short)f2bf(a.z); r[3] = (short)f2bf(a.w);
  r[4] = (short)f2bf(b.x); r[5] = (short)f2bf(b.y);
  r[6] = (short)f2bf(b.z); r[7] = (short)f2bf(b.w);
  return r;
}

// LDS W^T image, bf16, XOR-swizzled in 8-elem (16B) slots: elem = k ^ ((col&7)<<3)
__device__ __forceinline__ bf16x8 ldsfrag(const unsigned short* w, int S, int col, int k0) {
  return *reinterpret_cast<const bf16x8*>(w + col * S + (k0 ^ ((col & 7) << 3)));
}

// gather a B-fragment from a row-major global weight W[k][col], ld = row stride.
// per j, lanes are contiguous in col -> 2x128B coalesced segments. L2-hot.
__device__ __forceinline__ bf16x8 wfrag(const float* __restrict__ W, int ld, int col, int k0) {
  bf16x8 f;
#pragma unroll
  for (int j = 0; j < 8; ++j) f[j] = (short)f2bf(W[(size_t)(k0 + j) * ld + col]);
  return f;
}

__global__ __launch_bounds__(256, 3) void gcu_kernel(
    const float* __restrict__ z, const float* __restrict__ z_,
    const float* __restrict__ Wc, const float* __restrict__ bc,
    const float* __restrict__ Wn, const float* __restrict__ bn,
    const float* __restrict__ Wo, const float* __restrict__ bo,
    float* __restrict__ out, int N) {
  __shared__ __align__(16) unsigned short sWnT[64 * 128];   // 16 KB, shared by 4 waves
  __shared__ __align__(16) unsigned short sVV[4][16 * 128]; // 4 KB per wave

  const int tid = threadIdx.x;
  const int wid = tid >> 6, lane = tid & 63;
  const int lo = lane & 31, hi = lane >> 5;
  const int base = (blockIdx.x * 4 + wid) * 16;   // 16 nodes per wave-task
  unsigned short* vv = &sVV[wid][0];

  // ---- stage W_nbr^T (bf16, swizzled) into LDS, cooperative over 256 threads ----
  for (int i = tid; i < 128 * 64; i += 256) {
    int c = i & 63, k = i >> 6;                 // src Wn[k][c], coalesced over c
    sWnT[c * 128 + (k ^ ((c & 7) << 3))] = f2bf(Wn[i]);
  }

  // ---- stage this task's 16 z-rows as bf16 into vv cols 0..63 (fully coalesced) ----
  if (base < N) {
    int r = lane >> 2, seg = lane & 3;          // row in tile, 16-float segment
    int node = min(base + r, N - 1);
    const float* src = z + (size_t)node * 64 + seg * 16;
    float4 x0 = *reinterpret_cast<const float4*>(src);
    float4 x1 = *reinterpret_cast<const float4*>(src + 4);
    float4 x2 = *reinterpret_cast<const float4*>(src + 8);
    float4 x3 = *reinterpret_cast<const float4*>(src + 12);
    int m = (r & 7) << 3;
    *reinterpret_cast<bf16x8*>(vv + r * 128 + ((seg * 16)     ^ m)) = to_frag(x0, x1);
    *reinterpret_cast<bf16x8*>(vv + r * 128 + ((seg * 16 + 8) ^ m)) = to_frag(x2, x3);
  }
  __syncthreads();  // single barrier, before any divergence
  if (base >= N) return;

  const float bn0 = bn[lo], bn1 = bn[32 + lo];
  const float bc0 = bc[lo], bc1 = bc[32 + lo];
  const float bo0 = bo[lo], bo1 = bo[32 + lo];

  auto aptr_of = [&](int n) {
    return z_ + (size_t)min(base + n, N - 1) * 2048;
  };

  // per-node: S = (z_n || z_nbr) @ W_nbr, celu, col-sum over 32 nbrs -> vv[n][64..127]
  auto process = [&](const Stage& s, int n) {
    f32x16 acc0{}, acc1{};
#pragma unroll
    for (int ks = 0; ks < 8; ++ks) {
      bf16x8 af;
      if (ks < 4) {  // K-cols 0..63: broadcast z_n row from LDS (row-independent A)
        af = *reinterpret_cast<const bf16x8*>(
            vv + n * 128 + ((ks * 16 + 8 * hi) ^ ((n & 7) << 3)));
      } else {
        af = to_frag(s.a[ks - 4][0], s.a[ks - 4][1]);
      }
      bf16x8 b0 = ldsfrag(sWnT, 128, lo,      ks * 16 + 8 * hi);
      bf16x8 b1 = ldsfrag(sWnT, 128, lo + 32, ks * 16 + 8 * hi);
      acc0 = __builtin_amdgcn_mfma_f32_32x32x16_bf16(af, b0, acc0, 0, 0, 0);
      acc1 = __builtin_amdgcn_mfma_f32_32x32x16_bf16(af, b1, acc1, 0, 0, 0);
    }
    float s0 = 0.f, s1 = 0.f;
#pragma unroll
    for (int r = 0; r < 16; ++r) {              // C layout: col=lo, rows spread over regs+hi
      s0 += celu1(acc0[r] + bn0);
      s1 += celu1(acc1[r] + bn1);
    }
    s0 += __shfl_xor(s0, 32, 64);               // add other half's 16 rows
    s1 += __shfl_xor(s1, 32, 64);
    if (hi == 0) {
      vv[n * 128 + ((64 + lo) ^ ((n & 7) << 3))] = f2bf(s0);
      vv[n * 128 + ((96 + lo) ^ ((n & 7) << 3))] = f2bf(s1);
    }
  };

  Stage sA, sB;
  issue_stage(sA, aptr_of(0), lo, hi);
#pragma unroll 1
  for (int nn = 0; nn < 16; nn += 2) {
    issue_stage(sB, aptr_of(nn + 1), lo, hi);
    process(sA, nn);
    issue_stage(sA, aptr_of(nn + 2), lo, hi);   // nn+2==16 clamps into valid memory, discarded
    process(sB, nn + 1);
  }

  // ---- cur branch: v = celu(z @ W_cur + b_cur) -> vv[r][0..63] (rows duplicated via lo&15)
  {
    f32x16 a0{}, a1{};
    const int rl = lo & 15;
#pragma unroll
    for (int ks = 0; ks < 4; ++ks) {
      int k0 = ks * 16 + 8 * hi;
      bf16x8 af = *reinterpret_cast<const bf16x8*>(
          vv + rl * 128 + (k0 ^ ((rl & 7) << 3)));
      bf16x8 b0 = wfrag(Wc, 64, lo,      k0);
      bf16x8 b1 = wfrag(Wc, 64, lo + 32, k0);
      a0 = __builtin_amdgcn_mfma_f32_32x32x16_bf16(af, b0, a0, 0, 0, 0);
      a1 = __builtin_amdgcn_mfma_f32_32x32x16_bf16(af, b1, a1, 0, 0, 0);
    }
#pragma unroll
    for (int r = 0; r < 8; ++r) {               // rows 0..15 only (r>=8 are duplicates)
      int row = (r & 3) + 8 * (r >> 2) + 4 * hi;
      vv[row * 128 + ( lo        ^ ((row & 7) << 3))] = f2bf(celu1(a0[r] + bc0));
      vv[row * 128 + ((32 + lo)  ^ ((row & 7) << 3))] = f2bf(celu1(a1[r] + bc1));
    }
  }

  // ---- out: dc = (v || v_) @ W_out + b_out ----
  {
    f32x16 a0{}, a1{};
    const int rl = lo & 15;
#pragma unroll
    for (int ks = 0; ks < 8; ++ks) {
      int k0 = ks * 16 + 8 * hi;
      bf16x8 af = *reinterpret_cast<const bf16x8*>(
          vv + rl * 128 + (k0 ^ ((rl & 7) << 3)));
      bf16x8 b0 = wfrag(Wo, 64, lo,      k0);
      bf16x8 b1 = wfrag(Wo, 64, lo + 32, k0);
      a0 = __builtin_amdgcn_mfma_f32_32x32x16_bf16(af, b0, a0, 0, 0, 0);
      a1 = __builtin_amdgcn_mfma_f32_32x32x16_bf16(af, b1, a1, 0, 0, 0);
    }
#pragma unroll
    for (int r = 0; r < 8; ++r) {
      int row = base + (r & 3) + 8 * (r >> 2) + 4 * hi;
      if (row < N) {
        out[(size_t)row * 64 + lo]      = a0[r] + bo0;
        out[(size_t)row * 64 + 32 + lo] = a1[r] + bo1;
      }
    }
  }
}

extern "C" void kernel_launch(void* const* d_in, const int* in_sizes, int n_in,
                              void* d_out, int out_size, void* d_ws, size_t ws_size,
                              hipStream_t stream) {
  const float* z  = (const float*)d_in[0];
  const float* z_ = (const float*)d_in[1];
  const float* Wc = (const float*)d_in[2];
  const float* bc = (const float*)d_in[3];
  const float* Wn = (const float*)d_in[4];
  const float* bn = (const float*)d_in[5];
  const float* Wo = (const float*)d_in[6];
  const float* bo = (const float*)d_in[7];
  float* out = (float*)d_out;
  const int N = in_sizes[0] / 64;          // 50000
  const int tasks = (N + 15) / 16;         // 16 nodes per wave-task
  const int blocks = (tasks + 3) / 4;      // 4 waves per block -> 782 blocks
  gcu_kernel<<<blocks, 256, 0, stream>>>(z, z_, Wc, bc, Wn, bn, Wo, bo, out, N);
}

// Round 4
// 99.191 us; speedup vs baseline: 1.1920x; 1.1920x over previous
//
#include <hip/hip_runtime.h>
#include <hip/hip_bf16.h>

typedef float  f32x16 __attribute__((ext_vector_type(16)));
typedef short  bf16x8 __attribute__((ext_vector_type(8)));

__device__ __forceinline__ unsigned short f2bf(float x) {
  union { float f; unsigned u; } v; v.f = x;
  return (unsigned short)((v.u + 0x7FFFu + ((v.u >> 16) & 1u)) >> 16);
}
__device__ __forceinline__ float bf2f(unsigned short u) {
  union { unsigned u; float f; } v; v.u = ((unsigned)u) << 16; return v.f;
}
__device__ __forceinline__ float celu1(float x) {
  return x > 0.f ? x : (__expf(x) - 1.f);
}

struct Stage { float4 a[4][2]; };  // one node's 32x64 f32 nbr tile slice per lane

__device__ __forceinline__ void issue_stage(Stage& s, const float* __restrict__ aptr,
                                            int lo, int hi) {
#pragma unroll
  for (int ks = 0; ks < 4; ++ks) {
    const float* pa = aptr + lo * 64 + ks * 16 + 8 * hi;
    s.a[ks][0] = *reinterpret_cast<const float4*>(pa);
    s.a[ks][1] = *reinterpret_cast<const float4*>(pa + 4);
  }
}

__device__ __forceinline__ bf16x8 to_frag(float4 a, float4 b) {
  bf16x8 r;
  r[0] = (short)f2bf(a.x); r[1] = (short)f2bf(a.y);
  r[2] = (short)f2bf(a.z); r[3] = (short)f2bf(a.w);
  r[4] = (short)f2bf(b.x); r[5] = (short)f2bf(b.y);
  r[6] = (short)f2bf(b.z); r[7] = (short)f2bf(b.w);
  return r;
}

// LDS W^T image, bf16, XOR-swizzled in 8-elem (16B) slots: elem = k ^ ((col&7)<<3)
__device__ __forceinline__ bf16x8 ldsfrag(const unsigned short* w, int S, int col, int k0) {
  return *reinterpret_cast<const bf16x8*>(w + col * S + (k0 ^ ((col & 7) << 3)));
}

// B-fragment gathered from row-major global W[k][col]; coalesced 128B per j. L2-hot.
__device__ __forceinline__ bf16x8 wfrag(const float* __restrict__ W, int ld, int col, int k0) {
  bf16x8 f;
#pragma unroll
  for (int j = 0; j < 8; ++j) f[j] = (short)f2bf(W[(size_t)(k0 + j) * ld + col]);
  return f;
}

__global__ __launch_bounds__(256, 2) void gcu_kernel(
    const float* __restrict__ z, const float* __restrict__ z_,
    const float* __restrict__ Wc, const float* __restrict__ bc,
    const float* __restrict__ Wn, const float* __restrict__ bn,
    const float* __restrict__ Wo, const float* __restrict__ bo,
    float* __restrict__ out, int N) {
  __shared__ __align__(16) unsigned short sWnT[64 * 128];    // 16 KB, block-shared
  __shared__ __align__(16) unsigned short sVV[4][32 * 128];  // 8 KB / wave (z -> v | v_)
  __shared__ __align__(16) unsigned short sT[4][32 * 64];    // 4 KB / wave (self-half, bf16)

  const int tid = threadIdx.x;
  const int wid = tid >> 6, lane = tid & 63;
  const int lo = lane & 31, hi = lane >> 5;

  // ---- stage W_nbr^T (bf16, swizzled) into LDS, cooperative over 256 threads ----
  for (int i = tid; i < 128 * 64; i += 256) {
    int c = i & 63, k = i >> 6;                 // src Wn[k][c], coalesced over c
    sWnT[c * 128 + (k ^ ((c & 7) << 3))] = f2bf(Wn[i]);
  }
  __syncthreads();  // single barrier, before any divergence

  // interleaved task mapping: every block gets 3-4 busy waves -> no CU phase imbalance
  const int task = blockIdx.x + (int)gridDim.x * wid;
  const int base = task * 32;
  if (base >= N) return;

  unsigned short* vv = &sVV[wid][0];
  unsigned short* tt = &sT[wid][0];

  // ---- stage this task's 32 z-rows bf16 into vv cols 0..63 (same-wave use only) ----
  {
    int r = lane >> 1, seg = lane & 1;
    int node = min(base + r, N - 1);
    const float* src = z + (size_t)node * 64 + seg * 32;
    int m = (r & 7) << 3;
#pragma unroll
    for (int q = 0; q < 4; ++q) {
      float4 x0 = *reinterpret_cast<const float4*>(src + q * 8);
      float4 x1 = *reinterpret_cast<const float4*>(src + q * 8 + 4);
      *reinterpret_cast<bf16x8*>(vv + r * 128 + ((seg * 32 + q * 8) ^ m)) = to_frag(x0, x1);
    }
  }

  const float bn0 = bn[lo], bn1 = bn[32 + lo];
  const float bc0 = bc[lo], bc1 = bc[32 + lo];
  const float bo0 = bo[lo], bo1 = bo[32 + lo];

  // ---- T = Z_tile @ Wn_top (self-half of the concat GEMM, once per task) ----
  {
    f32x16 a0{}, a1{};
#pragma unroll
    for (int ks = 0; ks < 4; ++ks) {
      int k0 = ks * 16 + 8 * hi;
      bf16x8 af = *reinterpret_cast<const bf16x8*>(vv + lo * 128 + (k0 ^ ((lo & 7) << 3)));
      bf16x8 b0 = ldsfrag(sWnT, 128, lo, k0);
      bf16x8 b1 = ldsfrag(sWnT, 128, lo + 32, k0);
      a0 = __builtin_amdgcn_mfma_f32_32x32x16_bf16(af, b0, a0, 0, 0, 0);
      a1 = __builtin_amdgcn_mfma_f32_32x32x16_bf16(af, b1, a1, 0, 0, 0);
    }
#pragma unroll
    for (int r = 0; r < 16; ++r) {
      int row = (r & 3) + 8 * (r >> 2) + 4 * hi;
      tt[row * 64 + lo]      = f2bf(a0[r]);
      tt[row * 64 + 32 + lo] = f2bf(a1[r]);
    }
  }

  // ---- hoist Wn_bot^T B-fragments (constant across all 32 nodes) into VGPRs ----
  bf16x8 Bn[4][2];
#pragma unroll
  for (int ks = 0; ks < 4; ++ks) {
    int k0 = 64 + ks * 16 + 8 * hi;
    Bn[ks][0] = ldsfrag(sWnT, 128, lo, k0);
    Bn[ks][1] = ldsfrag(sWnT, 128, lo + 32, k0);
  }

  auto aptr_of = [&](int n) { return z_ + (size_t)min(base + n, N - 1) * 2048; };

  // per node: S = T[n] + Z_nbr @ Wn_bot + bn; v_[n] = sum_rows celu(S) -> vv[n][64..127]
  auto process = [&](const Stage& s, int n) {
    float c0 = bn0 + bf2f(tt[n * 64 + lo]);
    float c1 = bn1 + bf2f(tt[n * 64 + 32 + lo]);
    f32x16 acc0{}, acc1{};
#pragma unroll
    for (int ks = 0; ks < 4; ++ks) {
      bf16x8 af = to_frag(s.a[ks][0], s.a[ks][1]);
      acc0 = __builtin_amdgcn_mfma_f32_32x32x16_bf16(af, Bn[ks][0], acc0, 0, 0, 0);
      acc1 = __builtin_amdgcn_mfma_f32_32x32x16_bf16(af, Bn[ks][1], acc1, 0, 0, 0);
    }
    float s0 = 0.f, s1 = 0.f;
#pragma unroll
    for (int r = 0; r < 16; ++r) {              // C layout: col=lo, rows spread over regs+hi
      s0 += celu1(acc0[r] + c0);
      s1 += celu1(acc1[r] + c1);
    }
    s0 += __shfl_xor(s0, 32, 64);               // add other half's 16 rows
    s1 += __shfl_xor(s1, 32, 64);
    if (hi == 0) {
      vv[n * 128 + ((64 + lo) ^ ((n & 7) << 3))] = f2bf(s0);
      vv[n * 128 + ((96 + lo) ^ ((n & 7) << 3))] = f2bf(s1);
    }
  };

  Stage sA, sB;
  issue_stage(sA, aptr_of(0), lo, hi);
#pragma unroll 1
  for (int nn = 0; nn < 32; nn += 2) {
    issue_stage(sB, aptr_of(nn + 1), lo, hi);
    process(sA, nn);
    issue_stage(sA, aptr_of(nn + 2), lo, hi);   // nn+2==32 clamps to valid memory, discarded
    process(sB, nn + 1);
  }

  // ---- cur branch: v = celu(z @ W_cur + b_cur) -> vv[r][0..63] (overwrites z image) ----
  {
    f32x16 a0{}, a1{};
#pragma unroll
    for (int ks = 0; ks < 4; ++ks) {
      int k0 = ks * 16 + 8 * hi;
      bf16x8 af = *reinterpret_cast<const bf16x8*>(vv + lo * 128 + (k0 ^ ((lo & 7) << 3)));
      bf16x8 b0 = wfrag(Wc, 64, lo, k0);
      bf16x8 b1 = wfrag(Wc, 64, lo + 32, k0);
      a0 = __builtin_amdgcn_mfma_f32_32x32x16_bf16(af, b0, a0, 0, 0, 0);
      a1 = __builtin_amdgcn_mfma_f32_32x32x16_bf16(af, b1, a1, 0, 0, 0);
    }
#pragma unroll
    for (int r = 0; r < 16; ++r) {
      int row = (r & 3) + 8 * (r >> 2) + 4 * hi;
      vv[row * 128 + ( lo       ^ ((row & 7) << 3))] = f2bf(celu1(a0[r] + bc0));
      vv[row * 128 + ((32 + lo) ^ ((row & 7) << 3))] = f2bf(celu1(a1[r] + bc1));
    }
  }

  // ---- out: dc = (v || v_) @ W_out + b_out ----
  {
    f32x16 a0{}, a1{};
#pragma unroll
    for (int ks = 0; ks < 8; ++ks) {
      int k0 = ks * 16 + 8 * hi;
      bf16x8 af = *reinterpret_cast<const bf16x8*>(vv + lo * 128 + (k0 ^ ((lo & 7) << 3)));
      bf16x8 b0 = wfrag(Wo, 64, lo, k0);
      bf16x8 b1 = wfrag(Wo, 64, lo + 32, k0);
      a0 = __builtin_amdgcn_mfma_f32_32x32x16_bf16(af, b0, a0, 0, 0, 0);
      a1 = __builtin_amdgcn_mfma_f32_32x32x16_bf16(af, b1, a1, 0, 0, 0);
    }
#pragma unroll
    for (int r = 0; r < 16; ++r) {
      int row = base + (r & 3) + 8 * (r >> 2) + 4 * hi;
      if (row < N) {
        out[(size_t)row * 64 + lo]      = a0[r] + bo0;
        out[(size_t)row * 64 + 32 + lo] = a1[r] + bo1;
      }
    }
  }
}

extern "C" void kernel_launch(void* const* d_in, const int* in_sizes, int n_in,
                              void* d_out, int out_size, void* d_ws, size_t ws_size,
                              hipStream_t stream) {
  const float* z  = (const float*)d_in[0];
  const float* z_ = (const float*)d_in[1];
  const float* Wc = (const float*)d_in[2];
  const float* bc = (const float*)d_in[3];
  const float* Wn = (const float*)d_in[4];
  const float* bn = (const float*)d_in[5];
  const float* Wo = (const float*)d_in[6];
  const float* bo = (const float*)d_in[7];
  float* out = (float*)d_out;
  const int N = in_sizes[0] / 64;            // 50000
  const int tasks = (N + 31) / 32;           // 1563 wave-tasks
  int blocks = 512;                          // exactly 2 blocks/CU, uniform occupancy
  while (blocks * 4 < tasks) blocks += 256;  // general-N safety (no-op at N=50000)
  gcu_kernel<<<blocks, 256, 0, stream>>>(z, z_, Wc, bc, Wn, bn, Wo, bo, out, N);
}

// Round 5
// 96.514 us; speedup vs baseline: 1.2250x; 1.0277x over previous
//
#include <hip/hip_runtime.h>
#include <hip/hip_bf16.h>

typedef float  f32x16 __attribute__((ext_vector_type(16)));
typedef short  bf16x8 __attribute__((ext_vector_type(8)));

__device__ __forceinline__ unsigned short f2bf(float x) {
  union { float f; unsigned u; } v; v.f = x;
  return (unsigned short)((v.u + 0x7FFFu + ((v.u >> 16) & 1u)) >> 16);
}
__device__ __forceinline__ float bf2f(unsigned short u) {
  union { unsigned u; float f; } v; v.u = ((unsigned)u) << 16; return v.f;
}
__device__ __forceinline__ float celu1(float x) {
  return x > 0.f ? x : (__expf(x) - 1.f);
}

__device__ __forceinline__ bf16x8 to_frag(float4 a, float4 b) {
  bf16x8 r;
  r[0] = (short)f2bf(a.x); r[1] = (short)f2bf(a.y);
  r[2] = (short)f2bf(a.z); r[3] = (short)f2bf(a.w);
  r[4] = (short)f2bf(b.x); r[5] = (short)f2bf(b.y);
  r[6] = (short)f2bf(b.z); r[7] = (short)f2bf(b.w);
  return r;
}

// LDS W^T image, bf16, XOR-swizzled in 8-elem (16B) slots: elem = k ^ ((col&7)<<3)
__device__ __forceinline__ bf16x8 ldsfrag(const unsigned short* w, int S, int col, int k0) {
  return *reinterpret_cast<const bf16x8*>(w + col * S + (k0 ^ ((col & 7) << 3)));
}

// B-fragment gathered from row-major global W[k][col]; coalesced 128B per j. L2-hot.
__device__ __forceinline__ bf16x8 wfrag(const float* __restrict__ W, int ld, int col, int k0) {
  bf16x8 f;
#pragma unroll
  for (int j = 0; j < 8; ++j) f[j] = (short)f2bf(W[(size_t)(k0 + j) * ld + col]);
  return f;
}

__global__ __launch_bounds__(256, 2) void gcu_kernel(
    const float* __restrict__ z, const float* __restrict__ z_,
    const float* __restrict__ Wc, const float* __restrict__ bc,
    const float* __restrict__ Wn, const float* __restrict__ bn,
    const float* __restrict__ Wo, const float* __restrict__ bo,
    float* __restrict__ out, int N) {
  __shared__ __align__(16) unsigned short sWnT[64 * 128];   // 16 KB, block-shared
  __shared__ __align__(16) unsigned short sT[4][32 * 64];   // 16 KB, self-half partials
  __shared__ __align__(16) unsigned short sV[4][32 * 64];   // 16 KB, v_ image
  __shared__ __align__(16) float sTile[4][32 * 64];         // 32 KB, f32 nbr tile / v image

  const int tid = threadIdx.x;
  const int wid = tid >> 6, lane = tid & 63;
  const int lo = lane & 31, hi = lane >> 5;

  // ---- stage W_nbr^T (bf16, swizzled) into LDS ----
  for (int i = tid; i < 128 * 64; i += 256) {
    int c = i & 63, k = i >> 6;
    sWnT[c * 128 + (k ^ ((c & 7) << 3))] = f2bf(Wn[i]);
  }
  __syncthreads();  // single block barrier

  const int task = blockIdx.x + (int)gridDim.x * wid;  // balanced interleave
  const int base = task * 32;
  if (base >= N) return;

  unsigned short* tt = &sT[wid][0];
  unsigned short* sv = &sV[wid][0];
  float* tile = &sTile[wid][0];

  // per-lane pre-swizzled staging offsets (in floats). LDS slot L=i*64+lane holds
  // global slot row*16 + (t ^ (row&7)), row=L/16, t=L%15.. (t=L&15). Swizzle stays
  // inside each 128B half-row -> global coalescing preserved.
  const int rl = lane >> 4, tl = lane & 15;
  const int o0 = rl * 64 + ((tl ^ rl) << 2);  // even i: row&7 = rl
  const int o1 = o0 ^ 16;                     // odd  i: row&7 = rl+4 -> XOR slot bit2

  auto stage_tile = [&](const float* gb) {
#pragma unroll
    for (int i = 0; i < 8; ++i) {
      const float* src = gb + i * 256 + ((i & 1) ? o1 : o0);
      __builtin_amdgcn_global_load_lds(
          (const __attribute__((address_space(1))) unsigned*)src,
          (__attribute__((address_space(3))) unsigned*)(tile + i * 256),
          16, 0, 0);
    }
  };

  stage_tile(z_ + (size_t)base * 2048);  // prefetch node 0 (overlaps T-GEMM)

  const float bn0 = bn[lo], bn1 = bn[32 + lo];
  const float bc0 = bc[lo], bc1 = bc[32 + lo];
  const float bo0 = bo[lo], bo1 = bo[32 + lo];

  // ---- z-fragments for this task's 32 rows (strided, but once per task) ----
  bf16x8 zf[4];
  {
    int node = min(base + lo, N - 1);
    const float* zp = z + (size_t)node * 64;
#pragma unroll
    for (int ks = 0; ks < 4; ++ks) {
      float4 x0 = *reinterpret_cast<const float4*>(zp + ks * 16 + 8 * hi);
      float4 x1 = *reinterpret_cast<const float4*>(zp + ks * 16 + 8 * hi + 4);
      zf[ks] = to_frag(x0, x1);
    }
  }

  // ---- T = Z_tile @ Wn_top (self-half of concat GEMM, once per task) ----
  {
    f32x16 a0{}, a1{};
#pragma unroll
    for (int ks = 0; ks < 4; ++ks) {
      int k0 = ks * 16 + 8 * hi;
      bf16x8 b0 = ldsfrag(sWnT, 128, lo, k0);
      bf16x8 b1 = ldsfrag(sWnT, 128, lo + 32, k0);
      a0 = __builtin_amdgcn_mfma_f32_32x32x16_bf16(zf[ks], b0, a0, 0, 0, 0);
      a1 = __builtin_amdgcn_mfma_f32_32x32x16_bf16(zf[ks], b1, a1, 0, 0, 0);
    }
#pragma unroll
    for (int r = 0; r < 16; ++r) {
      int row = (r & 3) + 8 * (r >> 2) + 4 * hi;
      tt[row * 64 + lo]      = f2bf(a0[r]);
      tt[row * 64 + 32 + lo] = f2bf(a1[r]);
    }
  }

  // ---- hoist Wn_bot^T B-fragments into VGPRs ----
  bf16x8 Bn_[4][2];
#pragma unroll
  for (int ks = 0; ks < 4; ++ks) {
    int k0 = 64 + ks * 16 + 8 * hi;
    Bn_[ks][0] = ldsfrag(sWnT, 128, lo, k0);
    Bn_[ks][1] = ldsfrag(sWnT, 128, lo + 32, k0);
  }

  // task-invariant swizzled ds_read offsets (bytes): slot s = ks*4+2hi+p
  int roff[8];
#pragma unroll
  for (int ks = 0; ks < 4; ++ks)
#pragma unroll
    for (int p = 0; p < 2; ++p)
      roff[ks * 2 + p] = lo * 256 + (((ks * 4 + 2 * hi + p) ^ (lo & 7)) << 4);
  const char* tb = (const char*)tile;

#pragma unroll 1
  for (int nn = 0; nn < 32; ++nn) {
    asm volatile("s_waitcnt vmcnt(0)" ::: "memory");   // tile nn landed in LDS
    __builtin_amdgcn_sched_barrier(0);
    float4 q[8];
#pragma unroll
    for (int j = 0; j < 8; ++j) q[j] = *reinterpret_cast<const float4*>(tb + roff[j]);
    bf16x8 af[4];
#pragma unroll
    for (int ks = 0; ks < 4; ++ks) af[ks] = to_frag(q[2 * ks], q[2 * ks + 1]);
    asm volatile("s_waitcnt lgkmcnt(0)" ::: "memory"); // reads done -> safe overwrite
    __builtin_amdgcn_sched_barrier(0);
    if (nn < 31) stage_tile(z_ + (size_t)min(base + nn + 1, N - 1) * 2048);

    float c0 = bn0 + bf2f(tt[nn * 64 + lo]);
    float c1 = bn1 + bf2f(tt[nn * 64 + 32 + lo]);
    f32x16 acc0{}, acc1{};
#pragma unroll
    for (int ks = 0; ks < 4; ++ks) {
      acc0 = __builtin_amdgcn_mfma_f32_32x32x16_bf16(af[ks], Bn_[ks][0], acc0, 0, 0, 0);
      acc1 = __builtin_amdgcn_mfma_f32_32x32x16_bf16(af[ks], Bn_[ks][1], acc1, 0, 0, 0);
    }
    float s0 = 0.f, s1 = 0.f;
#pragma unroll
    for (int r = 0; r < 16; ++r) {
      s0 += celu1(acc0[r] + c0);
      s1 += celu1(acc1[r] + c1);
    }
    s0 += __shfl_xor(s0, 32, 64);
    s1 += __shfl_xor(s1, 32, 64);
    if (hi == 0) {
      int m = (nn & 7) << 3;
      sv[nn * 64 + ( lo       ^ m)] = f2bf(s0);
      sv[nn * 64 + ((32 + lo) ^ m)] = f2bf(s1);
    }
  }

  // ---- cur branch: v = celu(z @ W_cur + b_cur) -> v image in (dead) tile buffer ----
  unsigned short* vt = (unsigned short*)tile;
  {
    f32x16 a0{}, a1{};
#pragma unroll
    for (int ks = 0; ks < 4; ++ks) {
      int k0 = ks * 16 + 8 * hi;
      a0 = __builtin_amdgcn_mfma_f32_32x32x16_bf16(zf[ks], wfrag(Wc, 64, lo, k0), a0, 0, 0, 0);
      a1 = __builtin_amdgcn_mfma_f32_32x32x16_bf16(zf[ks], wfrag(Wc, 64, lo + 32, k0), a1, 0, 0, 0);
    }
#pragma unroll
    for (int r = 0; r < 16; ++r) {
      int row = (r & 3) + 8 * (r >> 2) + 4 * hi;
      int m = (row & 7) << 3;
      vt[row * 64 + ( lo       ^ m)] = f2bf(celu1(a0[r] + bc0));
      vt[row * 64 + ((32 + lo) ^ m)] = f2bf(celu1(a1[r] + bc1));
    }
  }

  // ---- out: dc = (v || v_) @ W_out + b_out ----
  {
    f32x16 a0{}, a1{};
    const int mm = (lo & 7) << 3;
#pragma unroll
    for (int ks = 0; ks < 8; ++ks) {
      int k0 = ks * 16 + 8 * hi;
      bf16x8 af;
      if (ks < 4) af = *reinterpret_cast<const bf16x8*>(vt + lo * 64 + ( k0        ^ mm));
      else        af = *reinterpret_cast<const bf16x8*>(sv + lo * 64 + ((k0 - 64)  ^ mm));
      a0 = __builtin_amdgcn_mfma_f32_32x32x16_bf16(af, wfrag(Wo, 64, lo, k0), a0, 0, 0, 0);
      a1 = __builtin_amdgcn_mfma_f32_32x32x16_bf16(af, wfrag(Wo, 64, lo + 32, k0), a1, 0, 0, 0);
    }
#pragma unroll
    for (int r = 0; r < 16; ++r) {
      int row = base + (r & 3) + 8 * (r >> 2) + 4 * hi;
      if (row < N) {
        out[(size_t)row * 64 + lo]      = a0[r] + bo0;
        out[(size_t)row * 64 + 32 + lo] = a1[r] + bo1;
      }
    }
  }
}

extern "C" void kernel_launch(void* const* d_in, const int* in_sizes, int n_in,
                              void* d_out, int out_size, void* d_ws, size_t ws_size,
                              hipStream_t stream) {
  const float* z  = (const float*)d_in[0];
  const float* z_ = (const float*)d_in[1];
  const float* Wc = (const float*)d_in[2];
  const float* bc = (const float*)d_in[3];
  const float* Wn = (const float*)d_in[4];
  const float* bn = (const float*)d_in[5];
  const float* Wo = (const float*)d_in[6];
  const float* bo = (const float*)d_in[7];
  float* out = (float*)d_out;
  const int N = in_sizes[0] / 64;            // 50000
  const int tasks = (N + 31) / 32;           // 1563 wave-tasks
  int blocks = 512;                          // 2 blocks/CU, uniform occupancy
  while (blocks * 4 < tasks) blocks += 256;  // general-N safety (no-op at N=50000)
  gcu_kernel<<<blocks, 256, 0, stream>>>(z, z_, Wc, bc, Wn, bn, Wo, bo, out, N);
}

// Round 6
// 92.273 us; speedup vs baseline: 1.2813x; 1.0460x over previous
//
#include <hip/hip_runtime.h>
#include <hip/hip_bf16.h>

typedef float  f32x16 __attribute__((ext_vector_type(16)));
typedef short  bf16x8 __attribute__((ext_vector_type(8)));

__device__ __forceinline__ unsigned short f2bf(float x) {
  union { float f; unsigned u; } v; v.f = x;
  return (unsigned short)((v.u + 0x7FFFu + ((v.u >> 16) & 1u)) >> 16);
}
__device__ __forceinline__ float bf2f(unsigned short u) {
  union { unsigned u; float f; } v; v.u = ((unsigned)u) << 16; return v.f;
}
__device__ __forceinline__ float celu1(float x) {
  return x > 0.f ? x : (__expf(x) - 1.f);
}

__device__ __forceinline__ bf16x8 to_frag(float4 a, float4 b) {
  bf16x8 r;
  r[0] = (short)f2bf(a.x); r[1] = (short)f2bf(a.y);
  r[2] = (short)f2bf(a.z); r[3] = (short)f2bf(a.w);
  r[4] = (short)f2bf(b.x); r[5] = (short)f2bf(b.y);
  r[6] = (short)f2bf(b.z); r[7] = (short)f2bf(b.w);
  return r;
}

// LDS W^T image, bf16, XOR-swizzled in 8-elem (16B) slots: elem = k ^ ((col&7)<<3)
__device__ __forceinline__ bf16x8 ldsfrag(const unsigned short* w, int S, int col, int k0) {
  return *reinterpret_cast<const bf16x8*>(w + col * S + (k0 ^ ((col & 7) << 3)));
}

// B-fragment gathered from row-major global W[k][col]; coalesced 128B per j. L2-hot.
__device__ __forceinline__ bf16x8 wfrag(const float* __restrict__ W, int ld, int col, int k0) {
  bf16x8 f;
#pragma unroll
  for (int j = 0; j < 8; ++j) f[j] = (short)f2bf(W[(size_t)(k0 + j) * ld + col]);
  return f;
}

__global__ __launch_bounds__(256, 2) void gcu_kernel(
    const float* __restrict__ z, const float* __restrict__ z_,
    const float* __restrict__ Wc, const float* __restrict__ bc,
    const float* __restrict__ Wn, const float* __restrict__ bn,
    const float* __restrict__ Wo, const float* __restrict__ bo,
    float* __restrict__ out, int N) {
  __shared__ __align__(16) unsigned short sWnT[64 * 128];   // 16 KB, block-shared
  __shared__ __align__(16) unsigned short sT[4][32 * 64];   // 16 KB, self-half partials
  __shared__ __align__(16) unsigned short sV[4][32 * 64];   // 16 KB, v_ image
  __shared__ __align__(16) float sTile[4][32 * 64];         // 32 KB, f32 nbr tile / v image

  const int tid = threadIdx.x;
  const int wid = tid >> 6, lane = tid & 63;
  const int lo = lane & 31, hi = lane >> 5;

  // ---- stage W_nbr^T (bf16, swizzled) into LDS ----
  for (int i = tid; i < 128 * 64; i += 256) {
    int c = i & 63, k = i >> 6;
    sWnT[c * 128 + (k ^ ((c & 7) << 3))] = f2bf(Wn[i]);
  }
  __syncthreads();  // single block barrier

  // balanced variable-size tasks: all 2048 waves busy, 24-25 nodes each
  const int gw = blockIdx.x * 4 + wid;            // global wave id, grid fixed at 512
  const int nwaves = (int)gridDim.x * 4;
  const int start = (int)((long long)gw * N / nwaves);
  const int end   = (int)((long long)(gw + 1) * N / nwaves);
  const int cnt = end - start;
  if (cnt <= 0) return;

  unsigned short* tt = &sT[wid][0];
  unsigned short* sv = &sV[wid][0];
  float* tile = &sTile[wid][0];

  // per-lane pre-swizzled staging offsets (floats); swizzle stays inside 128B half-rows
  const int rl = lane >> 4, tl = lane & 15;
  const int o0 = rl * 64 + ((tl ^ rl) << 2);
  const int o1 = o0 ^ 16;

  auto stage_tile = [&](const float* gb) {
#pragma unroll
    for (int i = 0; i < 8; ++i) {
      const float* src = gb + i * 256 + ((i & 1) ? o1 : o0);
      __builtin_amdgcn_global_load_lds(
          (const __attribute__((address_space(1))) unsigned*)src,
          (__attribute__((address_space(3))) unsigned*)(tile + i * 256),
          16, 0, 0);
    }
  };

  stage_tile(z_ + (size_t)start * 2048);  // prefetch node 0 (overlaps T-GEMM)

  const float bn0 = bn[lo], bn1 = bn[32 + lo];
  const float bc0 = bc[lo], bc1 = bc[32 + lo];
  const float bo0 = bo[lo], bo1 = bo[32 + lo];

  // ---- z-fragments for this task's rows (padded to 32 via clamp) ----
  bf16x8 zf[4];
  {
    int node = min(start + lo, N - 1);
    const float* zp = z + (size_t)node * 64;
#pragma unroll
    for (int ks = 0; ks < 4; ++ks) {
      float4 x0 = *reinterpret_cast<const float4*>(zp + ks * 16 + 8 * hi);
      float4 x1 = *reinterpret_cast<const float4*>(zp + ks * 16 + 8 * hi + 4);
      zf[ks] = to_frag(x0, x1);
    }
  }

  // ---- T = Z_tile @ Wn_top (self-half of concat GEMM, once per task) ----
  {
    f32x16 a0{}, a1{};
#pragma unroll
    for (int ks = 0; ks < 4; ++ks) {
      int k0 = ks * 16 + 8 * hi;
      bf16x8 b0 = ldsfrag(sWnT, 128, lo, k0);
      bf16x8 b1 = ldsfrag(sWnT, 128, lo + 32, k0);
      a0 = __builtin_amdgcn_mfma_f32_32x32x16_bf16(zf[ks], b0, a0, 0, 0, 0);
      a1 = __builtin_amdgcn_mfma_f32_32x32x16_bf16(zf[ks], b1, a1, 0, 0, 0);
    }
#pragma unroll
    for (int r = 0; r < 16; ++r) {
      int row = (r & 3) + 8 * (r >> 2) + 4 * hi;
      tt[row * 64 + lo]      = f2bf(a0[r]);
      tt[row * 64 + 32 + lo] = f2bf(a1[r]);
    }
  }

  // ---- hoist Wn_bot^T B-fragments into VGPRs ----
  bf16x8 Bn_[4][2];
#pragma unroll
  for (int ks = 0; ks < 4; ++ks) {
    int k0 = 64 + ks * 16 + 8 * hi;
    Bn_[ks][0] = ldsfrag(sWnT, 128, lo, k0);
    Bn_[ks][1] = ldsfrag(sWnT, 128, lo + 32, k0);
  }

  // task-invariant swizzled ds_read offsets (bytes): slot s = ks*4+2hi+p
  int roff[8];
#pragma unroll
  for (int ks = 0; ks < 4; ++ks)
#pragma unroll
    for (int p = 0; p < 2; ++p)
      roff[ks * 2 + p] = lo * 256 + (((ks * 4 + 2 * hi + p) ^ (lo & 7)) << 4);
  const char* tb = (const char*)tile;

#pragma unroll 1
  for (int nn = 0; nn < cnt; ++nn) {
    asm volatile("s_waitcnt vmcnt(0)" ::: "memory");   // tile nn landed in LDS
    __builtin_amdgcn_sched_barrier(0);
    float4 q[8];
#pragma unroll
    for (int j = 0; j < 8; ++j) q[j] = *reinterpret_cast<const float4*>(tb + roff[j]);
    bf16x8 af[4];
#pragma unroll
    for (int ks = 0; ks < 4; ++ks) af[ks] = to_frag(q[2 * ks], q[2 * ks + 1]);
    asm volatile("s_waitcnt lgkmcnt(0)" ::: "memory"); // reads done -> safe overwrite
    __builtin_amdgcn_sched_barrier(0);
    if (nn + 1 < cnt) stage_tile(z_ + (size_t)(start + nn + 1) * 2048);

    float c0 = bn0 + bf2f(tt[nn * 64 + lo]);
    float c1 = bn1 + bf2f(tt[nn * 64 + 32 + lo]);
    f32x16 acc0{}, acc1{};
#pragma unroll
    for (int ks = 0; ks < 4; ++ks) {
      acc0 = __builtin_amdgcn_mfma_f32_32x32x16_bf16(af[ks], Bn_[ks][0], acc0, 0, 0, 0);
      acc1 = __builtin_amdgcn_mfma_f32_32x32x16_bf16(af[ks], Bn_[ks][1], acc1, 0, 0, 0);
    }
    float s0 = 0.f, s1 = 0.f;
#pragma unroll
    for (int r = 0; r < 16; ++r) {
      s0 += celu1(acc0[r] + c0);
      s1 += celu1(acc1[r] + c1);
    }
    s0 += __shfl_xor(s0, 32, 64);
    s1 += __shfl_xor(s1, 32, 64);
    if (hi == 0) {
      int m = (nn & 7) << 3;
      sv[nn * 64 + ( lo       ^ m)] = f2bf(s0);
      sv[nn * 64 + ((32 + lo) ^ m)] = f2bf(s1);
    }
  }

  // ---- cur branch: v = celu(z @ W_cur + b_cur) -> v image in (dead) tile buffer ----
  unsigned short* vt = (unsigned short*)tile;
  asm volatile("s_waitcnt vmcnt(0)" ::: "memory");  // last tile's DMA done before overwrite
  {
    f32x16 a0{}, a1{};
#pragma unroll
    for (int ks = 0; ks < 4; ++ks) {
      int k0 = ks * 16 + 8 * hi;
      a0 = __builtin_amdgcn_mfma_f32_32x32x16_bf16(zf[ks], wfrag(Wc, 64, lo, k0), a0, 0, 0, 0);
      a1 = __builtin_amdgcn_mfma_f32_32x32x16_bf16(zf[ks], wfrag(Wc, 64, lo + 32, k0), a1, 0, 0, 0);
    }
#pragma unroll
    for (int r = 0; r < 16; ++r) {
      int row = (r & 3) + 8 * (r >> 2) + 4 * hi;
      int m = (row & 7) << 3;
      vt[row * 64 + ( lo       ^ m)] = f2bf(celu1(a0[r] + bc0));
      vt[row * 64 + ((32 + lo) ^ m)] = f2bf(celu1(a1[r] + bc1));
    }
  }

  // ---- out: dc = (v || v_) @ W_out + b_out ----
  {
    f32x16 a0{}, a1{};
    const int mm = (lo & 7) << 3;
#pragma unroll
    for (int ks = 0; ks < 8; ++ks) {
      int k0 = ks * 16 + 8 * hi;
      bf16x8 af;
      if (ks < 4) af = *reinterpret_cast<const bf16x8*>(vt + lo * 64 + ( k0        ^ mm));
      else        af = *reinterpret_cast<const bf16x8*>(sv + lo * 64 + ((k0 - 64)  ^ mm));
      a0 = __builtin_amdgcn_mfma_f32_32x32x16_bf16(af, wfrag(Wo, 64, lo, k0), a0, 0, 0, 0);
      a1 = __builtin_amdgcn_mfma_f32_32x32x16_bf16(af, wfrag(Wo, 64, lo + 32, k0), a1, 0, 0, 0);
    }
#pragma unroll
    for (int r = 0; r < 16; ++r) {
      int row = start + (r & 3) + 8 * (r >> 2) + 4 * hi;
      if (row < end) {
        out[(size_t)row * 64 + lo]      = a0[r] + bo0;
        out[(size_t)row * 64 + 32 + lo] = a1[r] + bo1;
      }
    }
  }
}

extern "C" void kernel_launch(void* const* d_in, const int* in_sizes, int n_in,
                              void* d_out, int out_size, void* d_ws, size_t ws_size,
                              hipStream_t stream) {
  const float* z  = (const float*)d_in[0];
  const float* z_ = (const float*)d_in[1];
  const float* Wc = (const float*)d_in[2];
  const float* bc = (const float*)d_in[3];
  const float* Wn = (const float*)d_in[4];
  const float* bn = (const float*)d_in[5];
  const float* Wo = (const float*)d_in[6];
  const float* bo = (const float*)d_in[7];
  float* out = (float*)d_out;
  const int N = in_sizes[0] / 64;  // 50000
  // fixed 512 blocks (2/CU), 2048 waves; each wave owns a balanced contiguous node range
  gcu_kernel<<<512, 256, 0, stream>>>(z, z_, Wc, bc, Wn, bn, Wo, bo, out, N);
}